// Round 18
// baseline (239.117 us; speedup 1.0000x reference)
//
#include <hip/hip_runtime.h>
#include <hip/hip_bf16.h>

typedef __bf16 bf16;
typedef __bf16 bf16x4 __attribute__((ext_vector_type(4)));
typedef __bf16 bf16x8 __attribute__((ext_vector_type(8)));
typedef float  f32x4  __attribute__((ext_vector_type(4)));
typedef short  s16x4  __attribute__((ext_vector_type(4)));

#define DEVI __device__ __forceinline__

// B_=2048 windows, N=64 tokens, C=256, H=8 heads, HD=32, NW=64 windows/image
static constexpr float kScale = 0.17677669529663687f;  // 32^-0.5

DEVI f32x4 mfma32(bf16x8 a, bf16x8 b, f32x4 c) {
  return __builtin_amdgcn_mfma_f32_16x16x32_bf16(a, b, c, 0, 0, 0);
}
// K=16 bf16 MFMA; builtin is the "_1k" spelling; host pass falls to inline asm
// (parsed but never emitted: device-only function).
DEVI f32x4 mfma16(bf16x4 a, bf16x4 b, f32x4 c) {
#if __has_builtin(__builtin_amdgcn_mfma_f32_16x16x16bf16_1k)
  return __builtin_amdgcn_mfma_f32_16x16x16bf16_1k(
      __builtin_bit_cast(s16x4, a), __builtin_bit_cast(s16x4, b), c, 0, 0, 0);
#else
  f32x4 d;
  asm volatile("v_mfma_f32_16x16x16_bf16 %0, %1, %2, %3"
               : "=v"(d)
               : "v"(a), "v"(b), "v"(c));
  return d;
#endif
}
DEVI bf16x4 pk4(f32x4 v) {
  bf16x4 p;
  p[0] = (bf16)v[0]; p[1] = (bf16)v[1]; p[2] = (bf16)v[2]; p[3] = (bf16)v[3];
  return p;
}
// Async global->LDS DMA, 16 B/lane (HW adds lane*16 to the wave-uniform LDS
// base; global src is per-lane). vmcnt-tracked.
DEVI void load_lds16(const char* g, char* l) {
  __builtin_amdgcn_global_load_lds(
      (const __attribute__((address_space(1))) void*)g,
      (__attribute__((address_space(3))) void*)l, 16, 0, 0);
}
// Per-wave DMA completion fence. rule #18: hipcc can hoist LDS reads past an
// inline-asm waitcnt ("memory" doesn't order them) -> sched_barrier(0) after.
DEVI void wait_vm0() {
  asm volatile("s_waitcnt vmcnt(0)" ::: "memory");
  __builtin_amdgcn_sched_barrier(0);
}

// ---------------- prep (R11's layout: 32 chunks of 16 KB) ----------------
// wsall: chunks 0-23 = qkv (m*8 + k/32), 24-31 = wp (k/32).
// Chunk layout [256 n][64 B]: element (n, kk=k&31) at
//   n*64 + ((2*kk) ^ (slot(n)<<4)),  slot(n) = (n ^ (n>>2)) & 3  (2-way = free
//   banking on the 16B fragment reads). Swizzle baked into the global layout;
//   the kernel DMAs slices linearly (rule #21). q-scale folded into m=0.
// bqkv[m][n] (q-scaled).
// biasM[w64][h][i][j] = bf16(bias_table[rel_index[i][j]][h] + mask[w64][i][j]).
__global__ __launch_bounds__(256) void prep_kernel(
    const float* __restrict__ wq, const float* __restrict__ bq,
    const float* __restrict__ wk, const float* __restrict__ bk,
    const float* __restrict__ wv, const float* __restrict__ bv,
    const float* __restrict__ wp,
    const float* __restrict__ bias_table, const int* __restrict__ rel_index,
    const float* __restrict__ mask,
    char* __restrict__ wsall, float* __restrict__ bqkv, bf16* __restrict__ biasM) {
  int idx = blockIdx.x * 256 + threadIdx.x;
  if (idx < 196608) {                       // 3*256*256 qkv weights
    int m = idx >> 16, n = idx & 255, k = (idx >> 8) & 255;
    const float* w = (m == 0) ? wq : (m == 1 ? wk : wv);
    float v = w[k * 256 + n];
    if (m == 0) v *= kScale;
    int slot = (n ^ (n >> 2)) & 3;
    *(bf16*)(wsall + (size_t)(m * 8 + (k >> 5)) * 16384 + n * 64 +
             (((k & 31) * 2) ^ (slot << 4))) = (bf16)v;
  } else if (idx < 262144) {                // + 256*256 proj weight
    int rem = idx - 196608;
    int n = rem & 255, k = (rem >> 8) & 255;
    int slot = (n ^ (n >> 2)) & 3;
    *(bf16*)(wsall + (size_t)(24 + (k >> 5)) * 16384 + n * 64 +
             (((k & 31) * 2) ^ (slot << 4))) = (bf16)wp[k * 256 + n];
  } else if (idx < 262912) {                // + 3*256 biases
    int rem = idx - 262144;
    int m = rem >> 8, n = rem & 255;
    const float* b = (m == 0) ? bq : (m == 1 ? bk : bv);
    float v = b[n];
    if (m == 0) v *= kScale;
    bqkv[rem] = v;
  } else if (idx < 2360064) {               // + 64*8*64*64 fused bias+mask (bf16)
    int rem = idx - 262912;
    int w = rem >> 15, h = (rem >> 12) & 7, ij = rem & 4095;
    biasM[rem] = (bf16)(bias_table[rel_index[ij] * 8 + h] + mask[w * 4096 + ij]);
  }
}

// ---------------- fused swin attention block kernel (decoupled waves) --------
// Block = 1 window, 4 waves; wave s owns channels [64s,64s+64) = heads
// {2s,2s+1}. KEY CHANGE vs the 155.7µs champion: wave s only ever reads rows
// [s*64,s*64+64) of each weight chunk -> weight staging is WAVE-PRIVATE.
// Each wave DMAs its own 4 KB slice per BK=32 chunk into a private 2x4KB
// double buffer and fences with per-wave s_waitcnt vmcnt(0) — NO block
// barriers in the GEMM loops (champion had 16; lockstep waves could never
// fill each other's stalls). 3 barriers total. LDS 64 KB -> 2 independent
// blocks/CU on top of the intra-block decoupling.
// NOTE (R6/R8/R9/R11/R13/R14): demand ~190 regs (VGPR+AGPR unified) ->
// 2 waves/SIMD ceiling; min-wave launch_bounds >= 3 spill-dives to 84 VGPR.
__global__ __launch_bounds__(256) void swin_kernel(
    const float* __restrict__ x, const char* __restrict__ wsall,
    const float* __restrict__ bqkv, const float* __restrict__ bp,
    const bf16* __restrict__ biasM, float* __restrict__ out) {
  __shared__ __align__(16) char xs[32768];   // x (QKV phase), then obuf
  __shared__ __align__(16) char wbuf[32768]; // [4 waves][2 bufs][4 KB slice]

  int tid = threadIdx.x;
  int s = tid >> 6, lane = tid & 63;
  int g = lane >> 4, c = lane & 15;
  int win = blockIdx.x;
  const f32x4 fz = {0.f, 0.f, 0.f, 0.f};
  int slot = (c ^ (c >> 2)) & 3;             // slot(n) for n = s*64+nt*16+c
  char* wb = wbuf + s * 8192;                // this wave's private region

  // issue DMA: step-0 slice -> wb buf0 (x staging below covers the latency)
#pragma unroll
  for (int k = 0; k < 4; ++k)
    load_lds16(wsall + (size_t)s * 4096 + k * 1024 + lane * 16, wb + k * 1024);

  // ---- stage x window -> bf16 LDS [64 t][256 k], 512B rows, XOR swz ----
  {
    const char* xw = (const char*)(x + (size_t)win * 16384);
#pragma unroll
    for (int i = 0; i < 8; ++i) {
      int gb = i * 8192 + tid * 32;
      float4 f0 = *(const float4*)(xw + gb);
      float4 f1 = *(const float4*)(xw + gb + 16);
      bf16x8 v;
      v[0] = (bf16)f0.x; v[1] = (bf16)f0.y; v[2] = (bf16)f0.z; v[3] = (bf16)f0.w;
      v[4] = (bf16)f1.x; v[5] = (bf16)f1.y; v[6] = (bf16)f1.z; v[7] = (bf16)f1.w;
      int t = gb >> 10, ir = (gb & 1023) >> 1;
      *(bf16x8*)(xs + ((t * 512 + ir) ^ ((t & 7) << 4))) = v;
    }
  }
  __syncthreads();  // barrier 1: x staged (also drains step-0 DMA)

  bf16x4 qp[4][4], kp[4][4], vp[4][4];
  f32x4 acc[4][4];

  // ---- QKV: 24 wave-private steps (m = i>>3, kc = i&7), ZERO barriers ----
  for (int i = 0; i < 24; ++i) {
    int m = i >> 3, kc = i & 7;
    char* cur = wb + (i & 1) * 4096;
    if (i) wait_vm0();                       // step-i slice landed (per-wave)
    // issue DMA for step i+1 into the other private buffer
    {
      char* nb = wb + ((i + 1) & 1) * 4096;
#pragma unroll
      for (int k = 0; k < 4; ++k)
        load_lds16(wsall + (size_t)(i + 1) * 16384 + s * 4096 + k * 1024 + lane * 16,
                   nb + k * 1024);
    }
    if (kc == 0) {
      if (m < 2) {
#pragma unroll
        for (int nt = 0; nt < 4; ++nt) {
          f32x4 b4 = *(const f32x4*)(bqkv + m * 256 + s * 64 + nt * 16 + g * 4);
#pragma unroll
          for (int tt = 0; tt < 4; ++tt) acc[tt][nt] = b4;
        }
      } else {
#pragma unroll
        for (int nt = 0; nt < 4; ++nt) {
          float bv_ = bqkv[512 + s * 64 + nt * 16 + c];
          f32x4 b4 = {bv_, bv_, bv_, bv_};
#pragma unroll
          for (int tt = 0; tt < 4; ++tt) acc[tt][nt] = b4;
        }
      }
    }
    {
      bf16x8 xf[4], wf[4];
#pragma unroll
      for (int tt = 0; tt < 4; ++tt)
        xf[tt] = *(const bf16x8*)(
            xs + (((tt * 16 + c) * 512 + kc * 64 + g * 16) ^ ((c & 7) << 4)));
#pragma unroll
      for (int nt = 0; nt < 4; ++nt)
        wf[nt] = *(const bf16x8*)(
            cur + (nt * 16 + c) * 64 + ((g * 16) ^ (slot << 4)));
      if (m < 2) {
#pragma unroll
        for (int tt = 0; tt < 4; ++tt)
#pragma unroll
          for (int nt = 0; nt < 4; ++nt)
            acc[tt][nt] = mfma32(wf[nt], xf[tt], acc[tt][nt]);
      } else {
#pragma unroll
        for (int tt = 0; tt < 4; ++tt)
#pragma unroll
          for (int nt = 0; nt < 4; ++nt)
            acc[tt][nt] = mfma32(xf[tt], wf[nt], acc[tt][nt]);
      }
    }
    if (kc == 7) {
#pragma unroll
      for (int tt = 0; tt < 4; ++tt)
#pragma unroll
        for (int nt = 0; nt < 4; ++nt) {
          if (m == 0)      qp[tt][nt] = pk4(acc[tt][nt]);
          else if (m == 1) kp[tt][nt] = pk4(acc[tt][nt]);
          else             vp[tt][nt] = pk4(acc[tt][nt]);
        }
    }
  }
  __syncthreads();  // barrier 2: all waves' xs reads done; xs becomes obuf
                    // (step-24 DMA, issued at i=23, is drained here too)

  // ---- attention: fully in-register; outputs -> obuf (xs region) ----
#pragma unroll
  for (int hh = 0; hh < 2; ++hh) {
    int h = s * 2 + hh;
    const bf16* bm = biasM + ((size_t)(win & 63) * 8 + h) * 4096;
#pragma unroll
    for (int mi = 0; mi < 4; ++mi) {
      f32x4 sv[4];
#pragma unroll
      for (int mj = 0; mj < 4; ++mj) {
        bf16x4 b4 = *(const bf16x4*)(bm + (mi * 16 + c) * 64 + mj * 16 + g * 4);
        sv[mj] = (f32x4){(float)b4[0], (float)b4[1], (float)b4[2], (float)b4[3]};
      }
#pragma unroll
      for (int dd = 0; dd < 2; ++dd)
#pragma unroll
        for (int mj = 0; mj < 4; ++mj)
          sv[mj] = mfma16(kp[mj][hh * 2 + dd], qp[mi][hh * 2 + dd], sv[mj]);
      float mx;
      {
        f32x4 m4 = sv[0];
#pragma unroll
        for (int mj = 1; mj < 4; ++mj) {
          m4[0] = fmaxf(m4[0], sv[mj][0]); m4[1] = fmaxf(m4[1], sv[mj][1]);
          m4[2] = fmaxf(m4[2], sv[mj][2]); m4[3] = fmaxf(m4[3], sv[mj][3]);
        }
        mx = fmaxf(fmaxf(m4[0], m4[1]), fmaxf(m4[2], m4[3]));
        mx = fmaxf(mx, __shfl_xor(mx, 16));
        mx = fmaxf(mx, __shfl_xor(mx, 32));
      }
      float sum;
      {
        f32x4 s4 = fz;
#pragma unroll
        for (int mj = 0; mj < 4; ++mj) {
#pragma unroll
          for (int r = 0; r < 4; ++r) sv[mj][r] = __expf(sv[mj][r] - mx);
          s4 += sv[mj];
        }
        sum = (s4[0] + s4[1]) + (s4[2] + s4[3]);
        sum += __shfl_xor(sum, 16);
        sum += __shfl_xor(sum, 32);
      }
      float rs = 1.0f / sum;
      bf16x4 pf[4];
#pragma unroll
      for (int mj = 0; mj < 4; ++mj) pf[mj] = pk4(sv[mj]);
#pragma unroll
      for (int dt = 0; dt < 2; ++dt) {
        f32x4 o = fz;
#pragma unroll
        for (int mj = 0; mj < 4; ++mj)
          o = mfma16(vp[mj][hh * 2 + dt], pf[mj], o);
        bf16x4 ov;
        ov[0] = (bf16)(o[0] * rs); ov[1] = (bf16)(o[1] * rs);
        ov[2] = (bf16)(o[2] * rs); ov[3] = (bf16)(o[3] * rs);
        *(bf16x4*)(xs + (((mi * 16 + c) * 512 + (h * 32 + dt * 16 + g * 4) * 2) ^
                         ((c & 7) << 4))) = ov;
      }
    }
  }
  __syncthreads();  // barrier 3: obuf visible to all waves

  // ---- projection: 8 wave-private steps (chunks 24-31), zero barriers ----
  f32x4 acc2[4][4];
#pragma unroll
  for (int nt = 0; nt < 4; ++nt) {
    f32x4 b4 = *(const f32x4*)(bp + s * 64 + nt * 16 + g * 4);
#pragma unroll
    for (int tt = 0; tt < 4; ++tt) acc2[tt][nt] = b4;
  }
  for (int i = 24; i < 32; ++i) {
    int kc = i - 24;
    char* cur = wb + (i & 1) * 4096;
    wait_vm0();                              // step-i slice landed
    if (i < 31) {
      char* nb = wb + ((i + 1) & 1) * 4096;
#pragma unroll
      for (int k = 0; k < 4; ++k)
        load_lds16(wsall + (size_t)(i + 1) * 16384 + s * 4096 + k * 1024 + lane * 16,
                   nb + k * 1024);
    }
    {
      bf16x8 of[4], wf[4];
#pragma unroll
      for (int tt = 0; tt < 4; ++tt)
        of[tt] = *(const bf16x8*)(
            xs + (((tt * 16 + c) * 512 + kc * 64 + g * 16) ^ ((c & 7) << 4)));
#pragma unroll
      for (int nt = 0; nt < 4; ++nt)
        wf[nt] = *(const bf16x8*)(
            cur + (nt * 16 + c) * 64 + ((g * 16) ^ (slot << 4)));
#pragma unroll
      for (int tt = 0; tt < 4; ++tt)
#pragma unroll
        for (int nt = 0; nt < 4; ++nt)
          acc2[tt][nt] = mfma32(wf[nt], of[tt], acc2[tt][nt]);
    }
  }
  // store: C[n][t] -> out[win*64 + t][n], f32x4 along n
#pragma unroll
  for (int tt = 0; tt < 4; ++tt)
#pragma unroll
    for (int nt = 0; nt < 4; ++nt)
      *(f32x4*)(out + ((size_t)win * 64 + tt * 16 + c) * 256 + s * 64 + nt * 16 + g * 4) =
          acc2[tt][nt];
}

extern "C" void kernel_launch(void* const* d_in, const int* in_sizes, int n_in,
                              void* d_out, int out_size, void* d_ws, size_t ws_size,
                              hipStream_t stream) {
  const float* x          = (const float*)d_in[0];
  const float* mask       = (const float*)d_in[1];
  const float* wq         = (const float*)d_in[2];
  const float* bq         = (const float*)d_in[3];
  const float* wk         = (const float*)d_in[4];
  const float* bk         = (const float*)d_in[5];
  const float* wv         = (const float*)d_in[6];
  const float* bv         = (const float*)d_in[7];
  const float* wp         = (const float*)d_in[8];
  const float* bp         = (const float*)d_in[9];
  const float* bias_table = (const float*)d_in[10];
  const int*   rel_index  = (const int*)d_in[11];

  // Workspace (~4.6 MB): wsall (32 x 16 KB) | bqkv | biasM (bf16)
  char* ws = (char*)d_ws;
  size_t o = 0;
  char* wsall = ws + o; o += (size_t)32 * 16384;
  float* bqkv = (float*)(ws + o); o += (size_t)768 * 4;
  bf16* biasM = (bf16*)(ws + o); o += (size_t)64 * 8 * 64 * 64 * 2;
  if (ws_size < o) return;

  prep_kernel<<<9219, 256, 0, stream>>>(wq, bq, wk, bk, wv, bv, wp,
                                        bias_table, rel_index, mask,
                                        wsall, bqkv, biasM);
  swin_kernel<<<2048, 256, 0, stream>>>(x, wsall, bqkv, bp, biasM, (float*)d_out);
}